// Round 4
// baseline (878.597 us; speedup 1.0000x reference)
//
#include <hip/hip_runtime.h>
#include <cstdint>
#include <cstddef>

#define N_NODES 4096
#define NFEAT   512
#define NHID    64
#define NCLASS  40
#define NHEADS  4
#define ALPHA_S 0.2f
#define MAXD    96
#define NBLK    1024

typedef __bf16 bf16x8 __attribute__((ext_vector_type(8)));
typedef float  f32x4  __attribute__((ext_vector_type(4)));

__device__ __forceinline__ float lrelu(float x) { return x > 0.f ? x : ALPHA_S * x; }

__device__ __forceinline__ unsigned short f2bf(float f) {
    unsigned u = __float_as_uint(f);
    u += 0x7fffu + ((u >> 16) & 1u);          // round-to-nearest-even
    return (unsigned short)(u >> 16);
}

__device__ __forceinline__ float wredmax(float m) {
    #pragma unroll
    for (int o = 32; o; o >>= 1) m = fmaxf(m, __shfl_xor(m, o));
    return m;
}
__device__ __forceinline__ float wredsum(float s) {
    #pragma unroll
    for (int o = 32; o; o >>= 1) s += __shfl_xor(s, o);
    return s;
}

// LDS union: max member 16.6KB -> 9 blocks/CU by LDS; wave-cap gives 4 blocks/CU.
union SMem {
    struct { unsigned short As[4096]; unsigned short Bs[4096]; } g;   // 16KB gemm tiles
    float stage[64][65];                                              // 16.6KB epilogue stage
    unsigned int bm[4][128];                                          // 2KB dedup bitmasks
    struct { unsigned short nb[MAXD]; float ev[NHEADS][MAXD]; } a1;   // attn layer 1
    struct { unsigned short nb[4][MAXD]; float ev[4][MAXD]; } a2;     // attn layer 2
};

// flat grid barrier: counter at bar[phase*64], flag at bar[phase*64+32] (128B apart).
// Both zeroed by hipMemsetAsync before every launch.
__device__ __forceinline__ void gridbar(int* bar, int phase) {
    __syncthreads();
    __threadfence();                         // release: drain this block's stores to device scope
    if (threadIdx.x == 0) {
        int* cntp = bar + phase * 64;
        int* flag = bar + phase * 64 + 32;
        int old = __hip_atomic_fetch_add(cntp, 1, __ATOMIC_ACQ_REL, __HIP_MEMORY_SCOPE_AGENT);
        if (old == NBLK - 1) {
            __hip_atomic_store(flag, 1, __ATOMIC_RELEASE, __HIP_MEMORY_SCOPE_AGENT);
        } else {
            while (!__hip_atomic_load(flag, __ATOMIC_ACQUIRE, __HIP_MEMORY_SCOPE_AGENT))
                __builtin_amdgcn_s_sleep(2);
        }
    }
    __syncthreads();
    __threadfence();                         // acquire: invalidate stale cached lines
}

// 64x64 bf16 MFMA tile: C_acc += A[64xK] @ B[64xK]^T, XOR-swizzled LDS, 16x16x32
__device__ __forceinline__ void gemm_tile(const unsigned short* __restrict__ Ab,
                                          const unsigned short* __restrict__ Bb,
                                          int K, unsigned short* As, unsigned short* Bs,
                                          f32x4 acc[2][2]) {
    const int tid = threadIdx.x;
    const int l = tid & 63;
    const int wid = tid >> 6;
    const int wr = wid >> 1, wc = wid & 1;
    int aoff[2][2], boff[2][2];
    #pragma unroll
    for (int f = 0; f < 2; ++f) {
        int r = wr * 32 + f * 16 + (l & 15);
        int c = wc * 32 + f * 16 + (l & 15);
        #pragma unroll
        for (int s = 0; s < 2; ++s) {
            int gk = (s << 2) + (l >> 4);
            aoff[f][s] = r * 64 + ((gk ^ (r & 7)) << 3);
            boff[f][s] = c * 64 + ((gk ^ (c & 7)) << 3);
        }
    }
    for (int k0 = 0; k0 < K; k0 += 64) {
        for (int g2 = tid; g2 < 512; g2 += 256) {
            int row = g2 >> 3, gc = g2 & 7;
            uint4 va = *reinterpret_cast<const uint4*>(Ab + (size_t)row * K + k0 + (gc << 3));
            *reinterpret_cast<uint4*>(As + row * 64 + ((gc ^ (row & 7)) << 3)) = va;
            uint4 vb = *reinterpret_cast<const uint4*>(Bb + (size_t)row * K + k0 + (gc << 3));
            *reinterpret_cast<uint4*>(Bs + row * 64 + ((gc ^ (row & 7)) << 3)) = vb;
        }
        __syncthreads();
        #pragma unroll
        for (int s = 0; s < 2; ++s) {
            bf16x8 av[2], bv[2];
            #pragma unroll
            for (int f = 0; f < 2; ++f) {
                av[f] = *reinterpret_cast<const bf16x8*>(As + aoff[f][s]);
                bv[f] = *reinterpret_cast<const bf16x8*>(Bs + boff[f][s]);
            }
            #pragma unroll
            for (int fa = 0; fa < 2; ++fa)
                #pragma unroll
                for (int fb = 0; fb < 2; ++fb)
                    acc[fa][fb] = __builtin_amdgcn_mfma_f32_16x16x32_bf16(
                        av[fa], bv[fb], acc[fa][fb], 0, 0, 0);
        }
        __syncthreads();
    }
}

__global__ __launch_bounds__(256, 4) void mega(
        const float* __restrict__ x, const int* __restrict__ ei, int E,
        const float* __restrict__ W1, const float* __restrict__ b1,
        const float* __restrict__ a1, const float* __restrict__ ab1,
        const float* __restrict__ Wo, const float* __restrict__ bo,
        const float* __restrict__ ao, const float* __restrict__ abo,
        int* bar, int* cnt, unsigned short* nbr_raw, unsigned short* nbr, int* deg,
        unsigned short* xb, unsigned short* Bt, unsigned short* Wot,
        float* Wh1, float* src1, float* dst1, unsigned short* hb,
        float* Who, float* srco, float* dsto, float* out) {
    __shared__ SMem sm;
    const int tid = threadIdx.x;
    const int l = tid & 63;
    const int wid = tid >> 6;

    // ---------------- P0: casts + edge scatter (cnt pre-zeroed by memset) --------
    for (int u = blockIdx.x; u < 1856; u += NBLK) {
        if (u < 1024) {                       // x -> bf16, 2048 floats per unit
            size_t idx = (size_t)u * 2048 + tid * 8;
            float4 v0 = *reinterpret_cast<const float4*>(x + idx);
            float4 v1 = *reinterpret_cast<const float4*>(x + idx + 4);
            uint4 o;
            o.x = (unsigned)f2bf(v0.x) | ((unsigned)f2bf(v0.y) << 16);
            o.y = (unsigned)f2bf(v0.z) | ((unsigned)f2bf(v0.w) << 16);
            o.z = (unsigned)f2bf(v1.x) | ((unsigned)f2bf(v1.y) << 16);
            o.w = (unsigned)f2bf(v1.z) | ((unsigned)f2bf(v1.w) << 16);
            *reinterpret_cast<uint4*>(xb + idx) = o;
        } else if (u < 1280) {                // W1 -> Bt[256][512] transposed
            int n = u - 1024;
            int h = n >> 6, c = n & 63;
            for (int k = tid; k < NFEAT; k += 256)
                Bt[(size_t)n * NFEAT + k] = f2bf(W1[(size_t)h * NFEAT * NHID + (size_t)k * NHID + c]);
        } else if (u < 1344) {                // Wo -> Wot[64][256], cols>=40 zero
            int n = u - 1280;
            unsigned short v = 0;
            if (n < NCLASS) v = f2bf(Wo[(size_t)tid * NCLASS + n]);
            Wot[(size_t)n * 256 + tid] = v;
        } else {                              // edge scatter into raw lists
            int t = (u - 1344) * 256 + tid;
            if (t < E) {
                int r = ei[t];
                int c = ei[E + t];
                int slot = atomicAdd(&cnt[r], 1);
                if (slot < MAXD) nbr_raw[(size_t)r * MAXD + slot] = (unsigned short)c;
            }
        }
    }
    gridbar(bar, 0);

    // ---------------- P1: gemm1 (blocks b%4==0) || dedup+sort (others) -----------
    if ((blockIdx.x & 3) == 0) {
        const int u = blockIdx.x >> 2;        // 0..255
        const int rt = u & 63, h = u >> 6;
        f32x4 acc[2][2] = {};
        gemm_tile(xb + (size_t)(rt * 64) * NFEAT, Bt + (size_t)(h * 64) * NFEAT,
                  NFEAT, sm.g.As, sm.g.Bs, acc);
        const int wr = wid >> 1, wc = wid & 1;
        #pragma unroll
        for (int fa = 0; fa < 2; ++fa)
            #pragma unroll
            for (int fb = 0; fb < 2; ++fb) {
                int col = wc * 32 + fb * 16 + (l & 15);
                float bias = b1[h * NHID + col];
                #pragma unroll
                for (int j = 0; j < 4; ++j) {
                    int row = wr * 32 + fa * 16 + ((l >> 4) << 2) + j;
                    float v = acc[fa][fb][j] + bias;
                    Wh1[((size_t)h * N_NODES + rt * 64 + row) * NHID + col] = v;
                    sm.stage[row][col] = v;
                }
            }
        __syncthreads();
        // fused src/dst projections from the staged tile
        for (int rr = 0; rr < 16; ++rr) {
            int row = wid * 16 + rr;
            float v = sm.stage[row][l];
            float s = v * a1[h * 2 * NHID + l];
            float d2 = v * a1[h * 2 * NHID + NHID + l];
            s = wredsum(s); d2 = wredsum(d2);
            if (l == 0) {
                src1[h * N_NODES + rt * 64 + row] = s;
                dst1[h * N_NODES + rt * 64 + row] = d2;
            }
        }
    } else {
        // dedup via per-wave LDS bitmask; output sorted -> deterministic
        int idx = blockIdx.x - (blockIdx.x >> 2) - 1;   // 0..767
        for (int u = idx; u < 1024; u += 768) {
            int i = u * 4 + wid;
            sm.bm[wid][2 * l] = 0;
            sm.bm[wid][2 * l + 1] = 0;
            __syncthreads();
            int dr = cnt[i]; if (dr > MAXD) dr = MAXD;
            for (int q = l; q < dr; q += 64) {
                int c = nbr_raw[(size_t)i * MAXD + q];
                atomicOr(&sm.bm[wid][c >> 5], 1u << (c & 31));
            }
            __syncthreads();
            unsigned long long wv = (unsigned long long)sm.bm[wid][2 * l]
                                  | ((unsigned long long)sm.bm[wid][2 * l + 1] << 32);
            int cpc = __popcll(wv);
            int pre = cpc;
            #pragma unroll
            for (int o = 1; o < 64; o <<= 1) {
                int v = __shfl_up(pre, o);
                if (l >= o) pre += v;
            }
            int total = __shfl(pre, 63);
            int basep = pre - cpc;
            if (l == 0) deg[i] = total;
            while (wv) {
                int b = __builtin_ctzll(wv); wv &= wv - 1;
                nbr[(size_t)i * MAXD + basep++] = (unsigned short)(l * 64 + b);
            }
            __syncthreads();
        }
    }
    gridbar(bar, 1);

    // ---------------- P2: attn layer 1 (4 rows/block, wave = head) ---------------
    for (int i = blockIdx.x; i < N_NODES; i += NBLK) {
        const int d = deg[i];
        for (int q = tid; q < d; q += 256) sm.a1.nb[q] = nbr[(size_t)i * MAXD + q];
        __syncthreads();
        const int h = wid;
        const float s_i = src1[h * N_NODES + i];
        const float ab = ab1[h];
        const float* __restrict__ dsth = dst1 + h * N_NODES;
        const float* __restrict__ Whh = Wh1 + (size_t)h * N_NODES * NHID;
        int j0 = (l < d) ? sm.a1.nb[l] : -1;
        int j1 = (l + 64 < d) ? sm.a1.nb[l + 64] : -1;
        float s0 = (j0 >= 0) ? lrelu(s_i + dsth[j0] + ab) : -1e30f;
        float s1 = (j1 >= 0) ? lrelu(s_i + dsth[j1] + ab) : -1e30f;
        float m = wredmax(fmaxf(s0, s1));
        float e0 = (j0 >= 0) ? __expf(s0 - m) : 0.f;
        float e1 = (j1 >= 0) ? __expf(s1 - m) : 0.f;
        if (j0 >= 0) sm.a1.ev[h][l] = e0;
        if (j1 >= 0) sm.a1.ev[h][l + 64] = e1;
        float lsum = wredsum(e0 + e1);
        float acc = 0.f;
        if (d == 0) {                          // lazy colmean fallback (P ~ 5e-11)
            float s = 0.f;
            for (int j = 0; j < N_NODES; ++j) s += Whh[(size_t)j * NHID + l];
            acc = s * (1.f / N_NODES);
        } else {
            #pragma unroll 8
            for (int q = 0; q < d; ++q)
                acc += sm.a1.ev[h][q] * Whh[(size_t)sm.a1.nb[q] * NHID + l];
            acc *= (1.f / lsum);
        }
        float o = acc > 0.f ? acc : __expf(acc) - 1.f;   // elu
        hb[(size_t)i * (NHEADS * NHID) + h * NHID + l] = f2bf(o);
        __syncthreads();
    }
    gridbar(bar, 2);

    // ---------------- P3: gemm2 + srco/dsto (blocks b%16==0) ---------------------
    if ((blockIdx.x & 15) == 0) {
        const int rt = blockIdx.x >> 4;       // 0..63
        f32x4 acc[2][2] = {};
        gemm_tile(hb + (size_t)(rt * 64) * (NHEADS * NHID), Wot,
                  NHEADS * NHID, sm.g.As, sm.g.Bs, acc);
        const int wr = wid >> 1, wc = wid & 1;
        #pragma unroll
        for (int fa = 0; fa < 2; ++fa)
            #pragma unroll
            for (int fb = 0; fb < 2; ++fb) {
                int col = wc * 32 + fb * 16 + (l & 15);
                if (col < NCLASS) {
                    float bias = bo[col];
                    #pragma unroll
                    for (int j = 0; j < 4; ++j) {
                        int row = wr * 32 + fa * 16 + ((l >> 4) << 2) + j;
                        float v = acc[fa][fb][j] + bias;
                        Who[(size_t)(rt * 64 + row) * NCLASS + col] = v;
                        sm.stage[row][col] = v;
                    }
                }
            }
        __syncthreads();
        for (int rr = 0; rr < 16; ++rr) {
            int row = wid * 16 + rr;
            float v = (l < NCLASS) ? sm.stage[row][l] : 0.f;
            float s = (l < NCLASS) ? v * ao[l] : 0.f;
            float d2 = (l < NCLASS) ? v * ao[NCLASS + l] : 0.f;
            s = wredsum(s); d2 = wredsum(d2);
            if (l == 0) {
                srco[rt * 64 + row] = s;
                dsto[rt * 64 + row] = d2;
            }
        }
    }
    gridbar(bar, 3);

    // ---------------- P4: attn layer 2 + elu + log_softmax (wave = row) ----------
    {
        const int i = blockIdx.x * 4 + wid;
        const int d = deg[i];
        unsigned short* nbw = sm.a2.nb[wid];
        for (int q = l; q < d; q += 64) nbw[q] = nbr[(size_t)i * MAXD + q];
        const float ab = abo[0];
        const float s_i = srco[i];
        int j0 = (l < d) ? nbw[l] : -1;
        int j1 = (l + 64 < d) ? nbw[l + 64] : -1;
        float s0 = (j0 >= 0) ? lrelu(s_i + dsto[j0] + ab) : -1e30f;
        float s1 = (j1 >= 0) ? lrelu(s_i + dsto[j1] + ab) : -1e30f;
        float m = wredmax(fmaxf(s0, s1));
        float e0 = (j0 >= 0) ? __expf(s0 - m) : 0.f;
        float e1 = (j1 >= 0) ? __expf(s1 - m) : 0.f;
        if (j0 >= 0) sm.a2.ev[wid][l] = e0;
        if (j1 >= 0) sm.a2.ev[wid][l + 64] = e1;
        float lsum = wredsum(e0 + e1);
        float acc = 0.f;
        if (d == 0) {
            if (l < NCLASS) {
                float s = 0.f;
                for (int j = 0; j < N_NODES; ++j) s += Who[(size_t)j * NCLASS + l];
                acc = s * (1.f / N_NODES);
            }
        } else if (l < NCLASS) {
            #pragma unroll 8
            for (int q = 0; q < d; ++q)
                acc += sm.a2.ev[wid][q] * Who[(size_t)nbw[q] * NCLASS + l];
            acc *= (1.f / lsum);
        }
        float v = acc > 0.f ? acc : __expf(acc) - 1.f;   // elu
        float xv = (l < NCLASS) ? v : -1e30f;
        float mx = wredmax(xv);
        float ex = (l < NCLASS) ? __expf(v - mx) : 0.f;
        ex = wredsum(ex);
        if (l < NCLASS) out[(size_t)i * NCLASS + l] = v - mx - logf(ex);
    }
}

// ---------------------------------------------------------------------------
extern "C" void kernel_launch(void* const* d_in, const int* in_sizes, int n_in,
                              void* d_out, int out_size, void* d_ws, size_t ws_size,
                              hipStream_t stream) {
    const float* x   = (const float*)d_in[0];
    const int*   ei  = (const int*)d_in[1];
    const float* W1  = (const float*)d_in[2];
    const float* b1  = (const float*)d_in[3];
    const float* a1  = (const float*)d_in[4];
    const float* ab1 = (const float*)d_in[5];
    const float* Wo  = (const float*)d_in[6];
    const float* bo  = (const float*)d_in[7];
    const float* ao  = (const float*)d_in[8];
    const float* abo = (const float*)d_in[9];
    float* out = (float*)d_out;
    const int E = in_sizes[1] / 2;

    char* base = (char*)d_ws;
    const size_t MB = 1024 * 1024;
    int*            bar     = (int*)(base);                       // 1KB   (memset)
    int*            cnt     = (int*)(base + 1024);                // 16KB  (memset)
    int*            deg     = (int*)(base + 32 * 1024);           // 16KB
    unsigned short* nbr_raw = (unsigned short*)(base + 48 * 1024);          // 768KB
    unsigned short* nbr     = (unsigned short*)(base + 48 * 1024 + 786432); // 768KB
    unsigned short* xb      = (unsigned short*)(base + 2 * MB);   // 4MB
    unsigned short* Bt      = (unsigned short*)(base + 6 * MB);   // 256KB
    unsigned short* Wot     = (unsigned short*)(base + 6 * MB + 262144);    // 32KB
    float*          Wh1     = (float*)(base + 7 * MB);            // 4MB
    float*          src1    = (float*)(base + 11 * MB);           // 64KB
    float*          dst1    = (float*)(base + 11 * MB + 65536);   // 64KB
    unsigned short* hb      = (unsigned short*)(base + 12 * MB);  // 2MB
    float*          Who     = (float*)(base + 14 * MB);           // 640KB
    float*          srco    = (float*)(base + 15 * MB);           // 16KB
    float*          dsto    = (float*)(base + 15 * MB + 16384);   // 16KB

    hipMemsetAsync(base, 0, 1024 + 16384, stream);    // bar + cnt
    mega<<<NBLK, 256, 0, stream>>>(x, ei, E, W1, b1, a1, ab1, Wo, bo, ao, abo,
                                   bar, cnt, nbr_raw, nbr, deg,
                                   xb, Bt, Wot, Wh1, src1, dst1, hb,
                                   Who, srco, dsto, out);
}

// Round 5
// 310.657 us; speedup vs baseline: 2.8282x; 2.8282x over previous
//
#include <hip/hip_runtime.h>
#include <cstdint>
#include <cstddef>

#define N_NODES 4096
#define NFEAT   512
#define NHID    64
#define NCLASS  40
#define NHEADS  4
#define ALPHA_S 0.2f
#define MAXD    96
#define NBLK    1024
#define NGRP    64           // barrier groups of 16 blocks

typedef __bf16 bf16x8 __attribute__((ext_vector_type(8)));
typedef float  f32x4  __attribute__((ext_vector_type(4)));

__device__ __forceinline__ float lrelu(float x) { return x > 0.f ? x : ALPHA_S * x; }

__device__ __forceinline__ unsigned short f2bf(float f) {
    unsigned u = __float_as_uint(f);
    u += 0x7fffu + ((u >> 16) & 1u);          // round-to-nearest-even
    return (unsigned short)(u >> 16);
}

__device__ __forceinline__ float wredmax(float m) {
    #pragma unroll
    for (int o = 32; o; o >>= 1) m = fmaxf(m, __shfl_xor(m, o));
    return m;
}
__device__ __forceinline__ float wredsum(float s) {
    #pragma unroll
    for (int o = 32; o; o >>= 1) s += __shfl_xor(s, o);
    return s;
}

// LDS union: max member 16.6KB -> 9 blocks/CU by LDS; wave-cap gives 4 blocks/CU.
union SMem {
    struct { unsigned short As[4096]; unsigned short Bs[4096]; } g;   // 16KB gemm tiles
    float stage[64][65];                                              // 16.6KB epilogue stage
    unsigned int bm[4][128];                                          // 2KB dedup bitmasks
    struct { unsigned short nb[MAXD]; float ev[NHEADS][MAXD]; } a1;   // attn layer 1
    struct { unsigned short nb[4][MAXD]; float ev[4][MAXD]; } a2;     // attn layer 2
};

// Two-level grid barrier, low contention. Per-phase layout (ints, 128B lines):
//   [0]=root counter | [32]=flag | [64 + g*32]=group-g counter (g = blockIdx>>4)
// phase stride = (2 + NGRP) * 32 = 2112 ints. All zeroed by one hipMemsetAsync.
// Arrivals: ACQ_REL RMW chain (group -> root) after __threadfence release.
// Pollers: RELAXED loads on the flag line (no invalidate per poll, no RMW
// interference) + s_sleep backoff; single ACQUIRE fence after exit.
__device__ __forceinline__ void gridbar(int* bar, int phase) {
    __syncthreads();
    if (threadIdx.x == 0) {
        int* base = bar + phase * 2112;
        int* root = base;
        int* flag = base + 32;
        int* grp  = base + 64 + (blockIdx.x >> 4) * 32;
        __threadfence();                       // release this block's prior stores
        int g = __hip_atomic_fetch_add(grp, 1, __ATOMIC_ACQ_REL, __HIP_MEMORY_SCOPE_AGENT);
        if (g == 15) {                         // last of the 16-block group
            int r = __hip_atomic_fetch_add(root, 1, __ATOMIC_ACQ_REL, __HIP_MEMORY_SCOPE_AGENT);
            if (r == NGRP - 1)
                __hip_atomic_store(flag, 1, __ATOMIC_RELEASE, __HIP_MEMORY_SCOPE_AGENT);
        }
        while (!__hip_atomic_load(flag, __ATOMIC_RELAXED, __HIP_MEMORY_SCOPE_AGENT))
            __builtin_amdgcn_s_sleep(8);
        __builtin_amdgcn_fence(__ATOMIC_ACQUIRE, "agent");
    }
    __syncthreads();
}

// 64x64 bf16 MFMA tile: C_acc += A[64xK] @ B[64xK]^T, XOR-swizzled LDS, 16x16x32
__device__ __forceinline__ void gemm_tile(const unsigned short* __restrict__ Ab,
                                          const unsigned short* __restrict__ Bb,
                                          int K, unsigned short* As, unsigned short* Bs,
                                          f32x4 acc[2][2]) {
    const int tid = threadIdx.x;
    const int l = tid & 63;
    const int wid = tid >> 6;
    const int wr = wid >> 1, wc = wid & 1;
    int aoff[2][2], boff[2][2];
    #pragma unroll
    for (int f = 0; f < 2; ++f) {
        int r = wr * 32 + f * 16 + (l & 15);
        int c = wc * 32 + f * 16 + (l & 15);
        #pragma unroll
        for (int s = 0; s < 2; ++s) {
            int gk = (s << 2) + (l >> 4);
            aoff[f][s] = r * 64 + ((gk ^ (r & 7)) << 3);
            boff[f][s] = c * 64 + ((gk ^ (c & 7)) << 3);
        }
    }
    for (int k0 = 0; k0 < K; k0 += 64) {
        for (int g2 = tid; g2 < 512; g2 += 256) {
            int row = g2 >> 3, gc = g2 & 7;
            uint4 va = *reinterpret_cast<const uint4*>(Ab + (size_t)row * K + k0 + (gc << 3));
            *reinterpret_cast<uint4*>(As + row * 64 + ((gc ^ (row & 7)) << 3)) = va;
            uint4 vb = *reinterpret_cast<const uint4*>(Bb + (size_t)row * K + k0 + (gc << 3));
            *reinterpret_cast<uint4*>(Bs + row * 64 + ((gc ^ (row & 7)) << 3)) = vb;
        }
        __syncthreads();
        #pragma unroll
        for (int s = 0; s < 2; ++s) {
            bf16x8 av[2], bv[2];
            #pragma unroll
            for (int f = 0; f < 2; ++f) {
                av[f] = *reinterpret_cast<const bf16x8*>(As + aoff[f][s]);
                bv[f] = *reinterpret_cast<const bf16x8*>(Bs + boff[f][s]);
            }
            #pragma unroll
            for (int fa = 0; fa < 2; ++fa)
                #pragma unroll
                for (int fb = 0; fb < 2; ++fb)
                    acc[fa][fb] = __builtin_amdgcn_mfma_f32_16x16x32_bf16(
                        av[fa], bv[fb], acc[fa][fb], 0, 0, 0);
        }
        __syncthreads();
    }
}

__global__ __launch_bounds__(256, 4) void mega(
        const float* __restrict__ x, const int* __restrict__ ei, int E,
        const float* __restrict__ W1, const float* __restrict__ b1,
        const float* __restrict__ a1, const float* __restrict__ ab1,
        const float* __restrict__ Wo, const float* __restrict__ bo,
        const float* __restrict__ ao, const float* __restrict__ abo,
        int* bar, int* cnt, unsigned short* nbr_raw, unsigned short* nbr, int* deg,
        unsigned short* xb, unsigned short* Bt, unsigned short* Wot,
        float* Wh1, float* src1, float* dst1, unsigned short* hb,
        float* Who, float* srco, float* dsto, float* out) {
    __shared__ SMem sm;
    const int tid = threadIdx.x;
    const int l = tid & 63;
    const int wid = tid >> 6;

    // ---------------- P0: casts + edge scatter (cnt pre-zeroed by memset) --------
    for (int u = blockIdx.x; u < 1856; u += NBLK) {
        if (u < 1024) {                       // x -> bf16, 2048 floats per unit
            size_t idx = (size_t)u * 2048 + tid * 8;
            float4 v0 = *reinterpret_cast<const float4*>(x + idx);
            float4 v1 = *reinterpret_cast<const float4*>(x + idx + 4);
            uint4 o;
            o.x = (unsigned)f2bf(v0.x) | ((unsigned)f2bf(v0.y) << 16);
            o.y = (unsigned)f2bf(v0.z) | ((unsigned)f2bf(v0.w) << 16);
            o.z = (unsigned)f2bf(v1.x) | ((unsigned)f2bf(v1.y) << 16);
            o.w = (unsigned)f2bf(v1.z) | ((unsigned)f2bf(v1.w) << 16);
            *reinterpret_cast<uint4*>(xb + idx) = o;
        } else if (u < 1280) {                // W1 -> Bt[256][512] transposed
            int n = u - 1024;
            int h = n >> 6, c = n & 63;
            for (int k = tid; k < NFEAT; k += 256)
                Bt[(size_t)n * NFEAT + k] = f2bf(W1[(size_t)h * NFEAT * NHID + (size_t)k * NHID + c]);
        } else if (u < 1344) {                // Wo -> Wot[64][256], cols>=40 zero
            int n = u - 1280;
            unsigned short v = 0;
            if (n < NCLASS) v = f2bf(Wo[(size_t)tid * NCLASS + n]);
            Wot[(size_t)n * 256 + tid] = v;
        } else {                              // edge scatter into raw lists
            int t = (u - 1344) * 256 + tid;
            if (t < E) {
                int r = ei[t];
                int c = ei[E + t];
                int slot = atomicAdd(&cnt[r], 1);
                if (slot < MAXD) nbr_raw[(size_t)r * MAXD + slot] = (unsigned short)c;
            }
        }
    }
    gridbar(bar, 0);

    // ---------------- P1: gemm1 (blocks b%4==0) || dedup+sort (others) -----------
    if ((blockIdx.x & 3) == 0) {
        const int u = blockIdx.x >> 2;        // 0..255
        const int rt = u & 63, h = u >> 6;
        f32x4 acc[2][2] = {};
        gemm_tile(xb + (size_t)(rt * 64) * NFEAT, Bt + (size_t)(h * 64) * NFEAT,
                  NFEAT, sm.g.As, sm.g.Bs, acc);
        const int wr = wid >> 1, wc = wid & 1;
        #pragma unroll
        for (int fa = 0; fa < 2; ++fa)
            #pragma unroll
            for (int fb = 0; fb < 2; ++fb) {
                int col = wc * 32 + fb * 16 + (l & 15);
                float bias = b1[h * NHID + col];
                #pragma unroll
                for (int j = 0; j < 4; ++j) {
                    int row = wr * 32 + fa * 16 + ((l >> 4) << 2) + j;
                    float v = acc[fa][fb][j] + bias;
                    Wh1[((size_t)h * N_NODES + rt * 64 + row) * NHID + col] = v;
                    sm.stage[row][col] = v;
                }
            }
        __syncthreads();
        // fused src/dst projections from the staged tile
        for (int rr = 0; rr < 16; ++rr) {
            int row = wid * 16 + rr;
            float v = sm.stage[row][l];
            float s = v * a1[h * 2 * NHID + l];
            float d2 = v * a1[h * 2 * NHID + NHID + l];
            s = wredsum(s); d2 = wredsum(d2);
            if (l == 0) {
                src1[h * N_NODES + rt * 64 + row] = s;
                dst1[h * N_NODES + rt * 64 + row] = d2;
            }
        }
    } else {
        // dedup via per-wave LDS bitmask; output sorted -> deterministic
        int idx = blockIdx.x - (blockIdx.x >> 2) - 1;   // 0..767
        for (int u = idx; u < 1024; u += 768) {
            int i = u * 4 + wid;
            sm.bm[wid][2 * l] = 0;
            sm.bm[wid][2 * l + 1] = 0;
            __syncthreads();
            int dr = cnt[i]; if (dr > MAXD) dr = MAXD;
            for (int q = l; q < dr; q += 64) {
                int c = nbr_raw[(size_t)i * MAXD + q];
                atomicOr(&sm.bm[wid][c >> 5], 1u << (c & 31));
            }
            __syncthreads();
            unsigned long long wv = (unsigned long long)sm.bm[wid][2 * l]
                                  | ((unsigned long long)sm.bm[wid][2 * l + 1] << 32);
            int cpc = __popcll(wv);
            int pre = cpc;
            #pragma unroll
            for (int o = 1; o < 64; o <<= 1) {
                int v = __shfl_up(pre, o);
                if (l >= o) pre += v;
            }
            int total = __shfl(pre, 63);
            int basep = pre - cpc;
            if (l == 0) deg[i] = total;
            while (wv) {
                int b = __builtin_ctzll(wv); wv &= wv - 1;
                nbr[(size_t)i * MAXD + basep++] = (unsigned short)(l * 64 + b);
            }
            __syncthreads();
        }
    }
    gridbar(bar, 1);

    // ---------------- P2: attn layer 1 (4 rows/block, wave = head) ---------------
    for (int i = blockIdx.x; i < N_NODES; i += NBLK) {
        const int d = deg[i];
        for (int q = tid; q < d; q += 256) sm.a1.nb[q] = nbr[(size_t)i * MAXD + q];
        __syncthreads();
        const int h = wid;
        const float s_i = src1[h * N_NODES + i];
        const float ab = ab1[h];
        const float* __restrict__ dsth = dst1 + h * N_NODES;
        const float* __restrict__ Whh = Wh1 + (size_t)h * N_NODES * NHID;
        int j0 = (l < d) ? sm.a1.nb[l] : -1;
        int j1 = (l + 64 < d) ? sm.a1.nb[l + 64] : -1;
        float s0 = (j0 >= 0) ? lrelu(s_i + dsth[j0] + ab) : -1e30f;
        float s1 = (j1 >= 0) ? lrelu(s_i + dsth[j1] + ab) : -1e30f;
        float m = wredmax(fmaxf(s0, s1));
        float e0 = (j0 >= 0) ? __expf(s0 - m) : 0.f;
        float e1 = (j1 >= 0) ? __expf(s1 - m) : 0.f;
        if (j0 >= 0) sm.a1.ev[h][l] = e0;
        if (j1 >= 0) sm.a1.ev[h][l + 64] = e1;
        float lsum = wredsum(e0 + e1);
        float acc = 0.f;
        if (d == 0) {                          // lazy colmean fallback (P ~ 5e-11)
            float s = 0.f;
            for (int j = 0; j < N_NODES; ++j) s += Whh[(size_t)j * NHID + l];
            acc = s * (1.f / N_NODES);
        } else {
            #pragma unroll 8
            for (int q = 0; q < d; ++q)
                acc += sm.a1.ev[h][q] * Whh[(size_t)sm.a1.nb[q] * NHID + l];
            acc *= (1.f / lsum);
        }
        float o = acc > 0.f ? acc : __expf(acc) - 1.f;   // elu
        hb[(size_t)i * (NHEADS * NHID) + h * NHID + l] = f2bf(o);
        __syncthreads();
    }
    gridbar(bar, 2);

    // ---------------- P3: gemm2 + srco/dsto (blocks b%16==0) ---------------------
    if ((blockIdx.x & 15) == 0) {
        const int rt = blockIdx.x >> 4;       // 0..63
        f32x4 acc[2][2] = {};
        gemm_tile(hb + (size_t)(rt * 64) * (NHEADS * NHID), Wot,
                  NHEADS * NHID, sm.g.As, sm.g.Bs, acc);
        const int wr = wid >> 1, wc = wid & 1;
        #pragma unroll
        for (int fa = 0; fa < 2; ++fa)
            #pragma unroll
            for (int fb = 0; fb < 2; ++fb) {
                int col = wc * 32 + fb * 16 + (l & 15);
                if (col < NCLASS) {
                    float bias = bo[col];
                    #pragma unroll
                    for (int j = 0; j < 4; ++j) {
                        int row = wr * 32 + fa * 16 + ((l >> 4) << 2) + j;
                        float v = acc[fa][fb][j] + bias;
                        Who[(size_t)(rt * 64 + row) * NCLASS + col] = v;
                        sm.stage[row][col] = v;
                    }
                }
            }
        __syncthreads();
        for (int rr = 0; rr < 16; ++rr) {
            int row = wid * 16 + rr;
            float v = (l < NCLASS) ? sm.stage[row][l] : 0.f;
            float s = (l < NCLASS) ? v * ao[l] : 0.f;
            float d2 = (l < NCLASS) ? v * ao[NCLASS + l] : 0.f;
            s = wredsum(s); d2 = wredsum(d2);
            if (l == 0) {
                srco[rt * 64 + row] = s;
                dsto[rt * 64 + row] = d2;
            }
        }
    }
    gridbar(bar, 3);

    // ---------------- P4: attn layer 2 + elu + log_softmax (wave = row) ----------
    {
        const int i = blockIdx.x * 4 + wid;
        const int d = deg[i];
        unsigned short* nbw = sm.a2.nb[wid];
        for (int q = l; q < d; q += 64) nbw[q] = nbr[(size_t)i * MAXD + q];
        const float ab = abo[0];
        const float s_i = srco[i];
        int j0 = (l < d) ? nbw[l] : -1;
        int j1 = (l + 64 < d) ? nbw[l + 64] : -1;
        float s0 = (j0 >= 0) ? lrelu(s_i + dsto[j0] + ab) : -1e30f;
        float s1 = (j1 >= 0) ? lrelu(s_i + dsto[j1] + ab) : -1e30f;
        float m = wredmax(fmaxf(s0, s1));
        float e0 = (j0 >= 0) ? __expf(s0 - m) : 0.f;
        float e1 = (j1 >= 0) ? __expf(s1 - m) : 0.f;
        if (j0 >= 0) sm.a2.ev[wid][l] = e0;
        if (j1 >= 0) sm.a2.ev[wid][l + 64] = e1;
        float lsum = wredsum(e0 + e1);
        float acc = 0.f;
        if (d == 0) {
            if (l < NCLASS) {
                float s = 0.f;
                for (int j = 0; j < N_NODES; ++j) s += Who[(size_t)j * NCLASS + l];
                acc = s * (1.f / N_NODES);
            }
        } else if (l < NCLASS) {
            #pragma unroll 8
            for (int q = 0; q < d; ++q)
                acc += sm.a2.ev[wid][q] * Who[(size_t)nbw[q] * NCLASS + l];
            acc *= (1.f / lsum);
        }
        float v = acc > 0.f ? acc : __expf(acc) - 1.f;   // elu
        float xv = (l < NCLASS) ? v : -1e30f;
        float mx = wredmax(xv);
        float ex = (l < NCLASS) ? __expf(v - mx) : 0.f;
        ex = wredsum(ex);
        if (l < NCLASS) out[(size_t)i * NCLASS + l] = v - mx - logf(ex);
    }
}

// ---------------------------------------------------------------------------
extern "C" void kernel_launch(void* const* d_in, const int* in_sizes, int n_in,
                              void* d_out, int out_size, void* d_ws, size_t ws_size,
                              hipStream_t stream) {
    const float* x   = (const float*)d_in[0];
    const int*   ei  = (const int*)d_in[1];
    const float* W1  = (const float*)d_in[2];
    const float* b1  = (const float*)d_in[3];
    const float* a1  = (const float*)d_in[4];
    const float* ab1 = (const float*)d_in[5];
    const float* Wo  = (const float*)d_in[6];
    const float* bo  = (const float*)d_in[7];
    const float* ao  = (const float*)d_in[8];
    const float* abo = (const float*)d_in[9];
    float* out = (float*)d_out;
    const int E = in_sizes[1] / 2;

    char* base = (char*)d_ws;
    const size_t MB = 1024 * 1024;
    // bar: 4 phases x 2112 ints = 33792 B; cnt: 16384 B. One memset covers both.
    int*            bar     = (int*)(base);                                 // 33792 B (memset)
    int*            cnt     = (int*)(base + 36 * 1024);                     // 16KB (memset)
    int*            deg     = (int*)(base + 56 * 1024);                     // 16KB
    unsigned short* nbr_raw = (unsigned short*)(base + 80 * 1024);          // 768KB
    unsigned short* nbr     = (unsigned short*)(base + 80 * 1024 + 786432); // 768KB
    unsigned short* xb      = (unsigned short*)(base + 2 * MB);             // 4MB
    unsigned short* Bt      = (unsigned short*)(base + 6 * MB);             // 256KB
    unsigned short* Wot     = (unsigned short*)(base + 6 * MB + 262144);    // 32KB
    float*          Wh1     = (float*)(base + 7 * MB);                      // 4MB
    float*          src1    = (float*)(base + 11 * MB);                     // 64KB
    float*          dst1    = (float*)(base + 11 * MB + 65536);             // 64KB
    unsigned short* hb      = (unsigned short*)(base + 12 * MB);            // 2MB
    float*          Who     = (float*)(base + 14 * MB);                     // 640KB
    float*          srco    = (float*)(base + 15 * MB);                     // 16KB
    float*          dsto    = (float*)(base + 15 * MB + 16384);             // 16KB

    hipMemsetAsync(base, 0, 36 * 1024 + 16384, stream);    // bar + cnt
    mega<<<NBLK, 256, 0, stream>>>(x, ei, E, W1, b1, a1, ab1, Wo, bo, ao, abo,
                                   bar, cnt, nbr_raw, nbr, deg,
                                   xb, Bt, Wot, Wh1, src1, dst1, hb,
                                   Who, srco, dsto, out);
}

// Round 6
// 71.781 us; speedup vs baseline: 12.2400x; 4.3278x over previous
//
#include <hip/hip_runtime.h>
#include <cstdint>
#include <cstddef>

#define N_NODES 4096
#define NFEAT   512
#define NHID    64
#define NCLASS  40
#define NHEADS  4
#define ALPHA_S 0.2f
#define MAXD    96

typedef __bf16 bf16x8 __attribute__((ext_vector_type(8)));
typedef float  f32x4  __attribute__((ext_vector_type(4)));

__device__ __forceinline__ float lrelu(float x) { return x > 0.f ? x : ALPHA_S * x; }

__device__ __forceinline__ unsigned short f2bf(float f) {
    unsigned u = __float_as_uint(f);
    u += 0x7fffu + ((u >> 16) & 1u);          // round-to-nearest-even
    return (unsigned short)(u >> 16);
}

__device__ __forceinline__ float wredmax(float m) {
    #pragma unroll
    for (int o = 32; o; o >>= 1) m = fmaxf(m, __shfl_xor(m, o));
    return m;
}
__device__ __forceinline__ float wredsum(float s) {
    #pragma unroll
    for (int o = 32; o; o >>= 1) s += __shfl_xor(s, o);
    return s;
}

// ---------------------------------------------------------------------------
// K1 prep: casts + edge scatter into raw per-row lists (cnt pre-zeroed).
// grid: 1024 (x cast) + 256 (Bt) + 64 (Wot) + 512 (scatter) = 1856
// ---------------------------------------------------------------------------
__global__ __launch_bounds__(256) void prep(const float* __restrict__ x,
                                            const int* __restrict__ ei, int E,
                                            const float* __restrict__ W1,
                                            const float* __restrict__ Wo,
                                            unsigned short* __restrict__ xb,
                                            unsigned short* __restrict__ Bt,
                                            unsigned short* __restrict__ Wot,
                                            int* __restrict__ cnt,
                                            unsigned short* __restrict__ nbr_raw) {
    const int u = blockIdx.x, tid = threadIdx.x;
    if (u < 1024) {                       // x -> bf16, 2048 floats per block
        size_t idx = (size_t)u * 2048 + tid * 8;
        float4 v0 = *reinterpret_cast<const float4*>(x + idx);
        float4 v1 = *reinterpret_cast<const float4*>(x + idx + 4);
        uint4 o;
        o.x = (unsigned)f2bf(v0.x) | ((unsigned)f2bf(v0.y) << 16);
        o.y = (unsigned)f2bf(v0.z) | ((unsigned)f2bf(v0.w) << 16);
        o.z = (unsigned)f2bf(v1.x) | ((unsigned)f2bf(v1.y) << 16);
        o.w = (unsigned)f2bf(v1.z) | ((unsigned)f2bf(v1.w) << 16);
        *reinterpret_cast<uint4*>(xb + idx) = o;
    } else if (u < 1280) {                // W1 -> Bt[256][512] transposed
        int n = u - 1024;
        int h = n >> 6, c = n & 63;
        for (int k = tid; k < NFEAT; k += 256)
            Bt[(size_t)n * NFEAT + k] = f2bf(W1[(size_t)h * NFEAT * NHID + (size_t)k * NHID + c]);
    } else if (u < 1344) {                // Wo -> Wot[64][256], cols>=40 zero
        int n = u - 1280;
        unsigned short v = 0;
        if (n < NCLASS) v = f2bf(Wo[(size_t)tid * NCLASS + n]);
        Wot[(size_t)n * 256 + tid] = v;
    } else {                              // edge scatter
        int t = (u - 1344) * 256 + tid;
        if (t < E) {
            int r = ei[t];
            int c = ei[E + t];
            int slot = atomicAdd(&cnt[r], 1);
            if (slot < MAXD) nbr_raw[(size_t)r * MAXD + slot] = (unsigned short)c;
        }
    }
}

// ---------------------------------------------------------------------------
// 64x64 bf16 MFMA tile: C_acc += A[64xK] @ B[64xK]^T, XOR-swizzled LDS, 16x16x32
// ---------------------------------------------------------------------------
__device__ __forceinline__ void gemm_tile(const unsigned short* __restrict__ Ab,
                                          const unsigned short* __restrict__ Bb,
                                          int K, unsigned short* As, unsigned short* Bs,
                                          f32x4 acc[2][2]) {
    const int tid = threadIdx.x;
    const int l = tid & 63;
    const int wid = tid >> 6;
    const int wr = wid >> 1, wc = wid & 1;
    int aoff[2][2], boff[2][2];
    #pragma unroll
    for (int f = 0; f < 2; ++f) {
        int r = wr * 32 + f * 16 + (l & 15);
        int c = wc * 32 + f * 16 + (l & 15);
        #pragma unroll
        for (int s = 0; s < 2; ++s) {
            int gk = (s << 2) + (l >> 4);
            aoff[f][s] = r * 64 + ((gk ^ (r & 7)) << 3);
            boff[f][s] = c * 64 + ((gk ^ (c & 7)) << 3);
        }
    }
    for (int k0 = 0; k0 < K; k0 += 64) {
        for (int g2 = tid; g2 < 512; g2 += 256) {
            int row = g2 >> 3, gc = g2 & 7;
            uint4 va = *reinterpret_cast<const uint4*>(Ab + (size_t)row * K + k0 + (gc << 3));
            *reinterpret_cast<uint4*>(As + row * 64 + ((gc ^ (row & 7)) << 3)) = va;
            uint4 vb = *reinterpret_cast<const uint4*>(Bb + (size_t)row * K + k0 + (gc << 3));
            *reinterpret_cast<uint4*>(Bs + row * 64 + ((gc ^ (row & 7)) << 3)) = vb;
        }
        __syncthreads();
        #pragma unroll
        for (int s = 0; s < 2; ++s) {
            bf16x8 av[2], bv[2];
            #pragma unroll
            for (int f = 0; f < 2; ++f) {
                av[f] = *reinterpret_cast<const bf16x8*>(As + aoff[f][s]);
                bv[f] = *reinterpret_cast<const bf16x8*>(Bs + boff[f][s]);
            }
            #pragma unroll
            for (int fa = 0; fa < 2; ++fa)
                #pragma unroll
                for (int fb = 0; fb < 2; ++fb)
                    acc[fa][fb] = __builtin_amdgcn_mfma_f32_16x16x32_bf16(
                        av[fa], bv[fb], acc[fa][fb], 0, 0, 0);
        }
        __syncthreads();
    }
}

union MidSMem {
    struct { unsigned short As[4096]; unsigned short Bs[4096]; } g;   // 16KB
    float stage[64][65];                                              // 16.6KB
    unsigned int bm[4][128];                                          // 2KB
};

// ---------------------------------------------------------------------------
// K2 mid: blocks 0..255 -> gemm1 (+fused src/dst); blocks 256..1023 -> dedup+sort
// ---------------------------------------------------------------------------
__global__ __launch_bounds__(256) void mid(const unsigned short* __restrict__ xb,
                                           const unsigned short* __restrict__ Bt,
                                           const float* __restrict__ b1,
                                           const float* __restrict__ a1,
                                           const int* __restrict__ cnt,
                                           const unsigned short* __restrict__ nbr_raw,
                                           float* __restrict__ Wh1,
                                           float* __restrict__ src1,
                                           float* __restrict__ dst1,
                                           int* __restrict__ deg,
                                           unsigned short* __restrict__ nbr) {
    __shared__ MidSMem sm;
    const int tid = threadIdx.x;
    const int l = tid & 63;
    const int wid = tid >> 6;

    if (blockIdx.x < 256) {
        const int u = blockIdx.x;
        const int rt = u & 63, h = u >> 6;
        f32x4 acc[2][2] = {};
        gemm_tile(xb + (size_t)(rt * 64) * NFEAT, Bt + (size_t)(h * 64) * NFEAT,
                  NFEAT, sm.g.As, sm.g.Bs, acc);
        const int wr = wid >> 1, wc = wid & 1;
        #pragma unroll
        for (int fa = 0; fa < 2; ++fa)
            #pragma unroll
            for (int fb = 0; fb < 2; ++fb) {
                int col = wc * 32 + fb * 16 + (l & 15);
                float bias = b1[h * NHID + col];
                #pragma unroll
                for (int j = 0; j < 4; ++j) {
                    int row = wr * 32 + fa * 16 + ((l >> 4) << 2) + j;
                    float v = acc[fa][fb][j] + bias;
                    Wh1[((size_t)h * N_NODES + rt * 64 + row) * NHID + col] = v;
                    sm.stage[row][col] = v;
                }
            }
        __syncthreads();
        for (int rr = 0; rr < 16; ++rr) {
            int row = wid * 16 + rr;
            float v = sm.stage[row][l];
            float s = v * a1[h * 2 * NHID + l];
            float d2 = v * a1[h * 2 * NHID + NHID + l];
            s = wredsum(s); d2 = wredsum(d2);
            if (l == 0) {
                src1[h * N_NODES + rt * 64 + row] = s;
                dst1[h * N_NODES + rt * 64 + row] = d2;
            }
        }
    } else {
        // dedup via per-wave LDS bitmask; sorted output -> deterministic
        int idx = blockIdx.x - 256;           // 0..767
        for (int u = idx; u < 1024; u += 768) {
            int i = u * 4 + wid;
            sm.bm[wid][2 * l] = 0;
            sm.bm[wid][2 * l + 1] = 0;
            __syncthreads();
            int dr = cnt[i]; if (dr > MAXD) dr = MAXD;
            for (int q = l; q < dr; q += 64) {
                int c = nbr_raw[(size_t)i * MAXD + q];
                atomicOr(&sm.bm[wid][c >> 5], 1u << (c & 31));
            }
            __syncthreads();
            unsigned long long wv = (unsigned long long)sm.bm[wid][2 * l]
                                  | ((unsigned long long)sm.bm[wid][2 * l + 1] << 32);
            int cpc = __popcll(wv);
            int pre = cpc;
            #pragma unroll
            for (int o = 1; o < 64; o <<= 1) {
                int v = __shfl_up(pre, o);
                if (l >= o) pre += v;
            }
            int total = __shfl(pre, 63);
            int basep = pre - cpc;
            if (l == 0) deg[i] = total;
            while (wv) {
                int b = __builtin_ctzll(wv); wv &= wv - 1;
                nbr[(size_t)i * MAXD + basep++] = (unsigned short)(l * 64 + b);
            }
            __syncthreads();
        }
    }
}

// ---------------------------------------------------------------------------
// K3 attn layer 1: block = row, wave = head, lane = feature; writes bf16 h
// ---------------------------------------------------------------------------
__global__ __launch_bounds__(256) void attn1(const float* __restrict__ Wh1,
                                             const float* __restrict__ src1,
                                             const float* __restrict__ dst1,
                                             const float* __restrict__ ab1,
                                             const int* __restrict__ deg,
                                             const unsigned short* __restrict__ nbr,
                                             unsigned short* __restrict__ hb) {
    __shared__ unsigned short nb[MAXD];
    __shared__ float ev[NHEADS][MAXD];
    const int i = blockIdx.x;
    const int tid = threadIdx.x;
    const int l = tid & 63;
    const int h = tid >> 6;
    const int d = deg[i];
    for (int q = tid; q < d; q += 256) nb[q] = nbr[(size_t)i * MAXD + q];
    __syncthreads();
    const float s_i = src1[h * N_NODES + i];
    const float ab = ab1[h];
    const float* __restrict__ dsth = dst1 + h * N_NODES;
    const float* __restrict__ Whh = Wh1 + (size_t)h * N_NODES * NHID;
    int j0 = (l < d) ? nb[l] : -1;
    int j1 = (l + 64 < d) ? nb[l + 64] : -1;
    float s0 = (j0 >= 0) ? lrelu(s_i + dsth[j0] + ab) : -1e30f;
    float s1 = (j1 >= 0) ? lrelu(s_i + dsth[j1] + ab) : -1e30f;
    float m = wredmax(fmaxf(s0, s1));
    float e0 = (j0 >= 0) ? __expf(s0 - m) : 0.f;
    float e1 = (j1 >= 0) ? __expf(s1 - m) : 0.f;
    if (j0 >= 0) ev[h][l] = e0;
    if (j1 >= 0) ev[h][l + 64] = e1;
    float lsum = wredsum(e0 + e1);
    float acc = 0.f;
    if (d == 0) {                          // lazy colmean fallback (P ~ 5e-11)
        float s = 0.f;
        for (int j = 0; j < N_NODES; ++j) s += Whh[(size_t)j * NHID + l];
        acc = s * (1.f / N_NODES);
    } else {
        #pragma unroll 8
        for (int q = 0; q < d; ++q)
            acc += ev[h][q] * Whh[(size_t)nb[q] * NHID + l];
        acc *= (1.f / lsum);
    }
    float o = acc > 0.f ? acc : __expf(acc) - 1.f;   // elu
    hb[(size_t)i * (NHEADS * NHID) + h * NHID + l] = f2bf(o);
}

// ---------------------------------------------------------------------------
// K4 gemm2 (+fused srco/dsto): grid 64, one 64-row tile each
// ---------------------------------------------------------------------------
__global__ __launch_bounds__(256) void gemm2(const unsigned short* __restrict__ hb,
                                             const unsigned short* __restrict__ Wot,
                                             const float* __restrict__ bo,
                                             const float* __restrict__ ao,
                                             float* __restrict__ Who,
                                             float* __restrict__ srco,
                                             float* __restrict__ dsto) {
    __shared__ MidSMem sm;
    const int tid = threadIdx.x;
    const int l = tid & 63;
    const int wid = tid >> 6;
    const int rt = blockIdx.x;
    f32x4 acc[2][2] = {};
    gemm_tile(hb + (size_t)(rt * 64) * (NHEADS * NHID), Wot,
              NHEADS * NHID, sm.g.As, sm.g.Bs, acc);
    const int wr = wid >> 1, wc = wid & 1;
    #pragma unroll
    for (int fa = 0; fa < 2; ++fa)
        #pragma unroll
        for (int fb = 0; fb < 2; ++fb) {
            int col = wc * 32 + fb * 16 + (l & 15);
            if (col < NCLASS) {
                float bias = bo[col];
                #pragma unroll
                for (int j = 0; j < 4; ++j) {
                    int row = wr * 32 + fa * 16 + ((l >> 4) << 2) + j;
                    float v = acc[fa][fb][j] + bias;
                    Who[(size_t)(rt * 64 + row) * NCLASS + col] = v;
                    sm.stage[row][col] = v;
                }
            }
        }
    __syncthreads();
    for (int rr = 0; rr < 16; ++rr) {
        int row = wid * 16 + rr;
        float v = (l < NCLASS) ? sm.stage[row][l] : 0.f;
        float s = (l < NCLASS) ? v * ao[l] : 0.f;
        float d2 = (l < NCLASS) ? v * ao[NCLASS + l] : 0.f;
        s = wredsum(s); d2 = wredsum(d2);
        if (l == 0) {
            srco[rt * 64 + row] = s;
            dsto[rt * 64 + row] = d2;
        }
    }
}

// ---------------------------------------------------------------------------
// K5 attn layer 2 + elu + log_softmax: 4 rows/block, wave = row
// ---------------------------------------------------------------------------
__global__ __launch_bounds__(256) void attn2(const float* __restrict__ Who,
                                             const float* __restrict__ srco,
                                             const float* __restrict__ dsto,
                                             const float* __restrict__ abo_p,
                                             const int* __restrict__ deg,
                                             const unsigned short* __restrict__ nbr,
                                             float* __restrict__ out) {
    __shared__ unsigned short nb[4][MAXD];
    __shared__ float ev[4][MAXD];
    const int tid = threadIdx.x;
    const int wid = tid >> 6;
    const int l = tid & 63;
    const int i = blockIdx.x * 4 + wid;
    const int d = deg[i];
    unsigned short* nbw = nb[wid];
    for (int q = l; q < d; q += 64) nbw[q] = nbr[(size_t)i * MAXD + q];
    const float ab = abo_p[0];
    const float s_i = srco[i];
    int j0 = (l < d) ? nbw[l] : -1;
    int j1 = (l + 64 < d) ? nbw[l + 64] : -1;
    float s0 = (j0 >= 0) ? lrelu(s_i + dsto[j0] + ab) : -1e30f;
    float s1 = (j1 >= 0) ? lrelu(s_i + dsto[j1] + ab) : -1e30f;
    float m = wredmax(fmaxf(s0, s1));
    float e0 = (j0 >= 0) ? __expf(s0 - m) : 0.f;
    float e1 = (j1 >= 0) ? __expf(s1 - m) : 0.f;
    if (j0 >= 0) ev[wid][l] = e0;
    if (j1 >= 0) ev[wid][l + 64] = e1;
    float lsum = wredsum(e0 + e1);
    float acc = 0.f;
    if (d == 0) {
        if (l < NCLASS) {
            float s = 0.f;
            for (int j = 0; j < N_NODES; ++j) s += Who[(size_t)j * NCLASS + l];
            acc = s * (1.f / N_NODES);
        }
    } else if (l < NCLASS) {
        #pragma unroll 8
        for (int q = 0; q < d; ++q)
            acc += ev[wid][q] * Who[(size_t)nbw[q] * NCLASS + l];
        acc *= (1.f / lsum);
    }
    float v = acc > 0.f ? acc : __expf(acc) - 1.f;   // elu
    float xv = (l < NCLASS) ? v : -1e30f;
    float mx = wredmax(xv);
    float ex = (l < NCLASS) ? __expf(v - mx) : 0.f;
    ex = wredsum(ex);
    if (l < NCLASS) out[(size_t)i * NCLASS + l] = v - mx - logf(ex);
}

// ---------------------------------------------------------------------------
extern "C" void kernel_launch(void* const* d_in, const int* in_sizes, int n_in,
                              void* d_out, int out_size, void* d_ws, size_t ws_size,
                              hipStream_t stream) {
    const float* x   = (const float*)d_in[0];
    const int*   ei  = (const int*)d_in[1];
    const float* W1  = (const float*)d_in[2];
    const float* b1  = (const float*)d_in[3];
    const float* a1  = (const float*)d_in[4];
    const float* ab1 = (const float*)d_in[5];
    const float* Wo  = (const float*)d_in[6];
    const float* bo  = (const float*)d_in[7];
    const float* ao  = (const float*)d_in[8];
    const float* abo = (const float*)d_in[9];
    float* out = (float*)d_out;
    const int E = in_sizes[1] / 2;

    char* base = (char*)d_ws;
    const size_t MB = 1024 * 1024;
    int*            cnt     = (int*)(base);                                 // 16KB (memset)
    int*            deg     = (int*)(base + 16 * 1024);                     // 16KB
    unsigned short* nbr_raw = (unsigned short*)(base + 32 * 1024);          // 768KB
    unsigned short* nbr     = (unsigned short*)(base + 32 * 1024 + 786432); // 768KB
    unsigned short* xb      = (unsigned short*)(base + 2 * MB);             // 4MB
    unsigned short* Bt      = (unsigned short*)(base + 6 * MB);             // 256KB
    unsigned short* Wot     = (unsigned short*)(base + 6 * MB + 262144);    // 32KB
    float*          Wh1     = (float*)(base + 7 * MB);                      // 4MB
    float*          src1    = (float*)(base + 11 * MB);                     // 64KB
    float*          dst1    = (float*)(base + 11 * MB + 65536);             // 64KB
    unsigned short* hb      = (unsigned short*)(base + 12 * MB);            // 2MB
    float*          Who     = (float*)(base + 14 * MB);                     // 640KB
    float*          srco    = (float*)(base + 15 * MB);                     // 16KB
    float*          dsto    = (float*)(base + 15 * MB + 16384);             // 16KB

    hipMemsetAsync(cnt, 0, 16 * 1024, stream);
    prep<<<1856, 256, 0, stream>>>(x, ei, E, W1, Wo, xb, Bt, Wot, cnt, nbr_raw);
    mid<<<1024, 256, 0, stream>>>(xb, Bt, b1, a1, cnt, nbr_raw, Wh1, src1, dst1, deg, nbr);
    attn1<<<N_NODES, 256, 0, stream>>>(Wh1, src1, dst1, ab1, deg, nbr, hb);
    gemm2<<<64, 256, 0, stream>>>(hb, Wot, bo, ao, Who, srco, dsto);
    attn2<<<N_NODES / 4, 256, 0, stream>>>(Who, srco, dsto, abo, deg, nbr, out);
}

// Round 7
// 69.370 us; speedup vs baseline: 12.6653x; 1.0347x over previous
//
#include <hip/hip_runtime.h>
#include <cstdint>
#include <cstddef>

#define N_NODES 4096
#define NFEAT   512
#define NHID    64
#define NCLASS  40
#define NHEADS  4
#define ALPHA_S 0.2f
#define MAXD    128

typedef __bf16 bf16x8 __attribute__((ext_vector_type(8)));
typedef float  f32x4  __attribute__((ext_vector_type(4)));

__device__ __forceinline__ float lrelu(float x) { return x > 0.f ? x : ALPHA_S * x; }

__device__ __forceinline__ unsigned short f2bf(float f) {
    unsigned u = __float_as_uint(f);
    u += 0x7fffu + ((u >> 16) & 1u);          // round-to-nearest-even
    return (unsigned short)(u >> 16);
}

__device__ __forceinline__ float wredmax(float m) {
    #pragma unroll
    for (int o = 32; o; o >>= 1) m = fmaxf(m, __shfl_xor(m, o));
    return m;
}
__device__ __forceinline__ float wredsum(float s) {
    #pragma unroll
    for (int o = 32; o; o >>= 1) s += __shfl_xor(s, o);
    return s;
}

// ---------------------------------------------------------------------------
// K1 prep: x->bf16 cast, W1->Bt transpose-cast, Wo->Wot pad-cast, adj zero.
// grid: 512 (x) + 256 (Bt) + 64 (Wot) + 128 (adj zero) = 960
// ---------------------------------------------------------------------------
__global__ __launch_bounds__(256) void prep(const float* __restrict__ x,
                                            const float* __restrict__ W1,
                                            const float* __restrict__ Wo,
                                            unsigned short* __restrict__ xb,
                                            unsigned short* __restrict__ Bt,
                                            unsigned short* __restrict__ Wot,
                                            uint4* __restrict__ adj4) {
    const int u = blockIdx.x, tid = threadIdx.x;
    if (u < 512) {                        // x -> bf16, 4096 floats per block
        size_t idx = (size_t)u * 4096 + tid * 16;
        #pragma unroll
        for (int half = 0; half < 2; ++half) {
            float4 v0 = *reinterpret_cast<const float4*>(x + idx + half * 8);
            float4 v1 = *reinterpret_cast<const float4*>(x + idx + half * 8 + 4);
            uint4 o;
            o.x = (unsigned)f2bf(v0.x) | ((unsigned)f2bf(v0.y) << 16);
            o.y = (unsigned)f2bf(v0.z) | ((unsigned)f2bf(v0.w) << 16);
            o.z = (unsigned)f2bf(v1.x) | ((unsigned)f2bf(v1.y) << 16);
            o.w = (unsigned)f2bf(v1.z) | ((unsigned)f2bf(v1.w) << 16);
            *reinterpret_cast<uint4*>(xb + idx + half * 8) = o;
        }
    } else if (u < 768) {                 // W1 -> Bt[256][512] transposed
        int n = u - 512;
        int h = n >> 6, c = n & 63;
        for (int k = tid; k < NFEAT; k += 256)
            Bt[(size_t)n * NFEAT + k] = f2bf(W1[(size_t)h * NFEAT * NHID + (size_t)k * NHID + c]);
    } else if (u < 832) {                 // Wo -> Wot[64][256], cols>=40 zero
        int n = u - 768;
        unsigned short v = 0;
        if (n < NCLASS) v = f2bf(Wo[(size_t)tid * NCLASS + n]);
        Wot[(size_t)n * 256 + tid] = v;
    } else {                              // zero adj: 128 blocks x 256 thr x 1 uint4... x4
        uint4 z = {0, 0, 0, 0};
        uint4* p = adj4 + (size_t)(u - 832) * 1024 + tid;
        p[0] = z; p[256] = z; p[512] = z; p[768] = z;
    }
}

// ---------------------------------------------------------------------------
// 64x64 bf16 MFMA tile: C_acc += A[64xK] @ B[64xK]^T, XOR-swizzled LDS, 16x16x32
// ---------------------------------------------------------------------------
__device__ __forceinline__ void gemm_tile(const unsigned short* __restrict__ Ab,
                                          const unsigned short* __restrict__ Bb,
                                          int K, unsigned short* As, unsigned short* Bs,
                                          f32x4 acc[2][2]) {
    const int tid = threadIdx.x;
    const int l = tid & 63;
    const int wid = tid >> 6;
    const int wr = wid >> 1, wc = wid & 1;
    int aoff[2][2], boff[2][2];
    #pragma unroll
    for (int f = 0; f < 2; ++f) {
        int r = wr * 32 + f * 16 + (l & 15);
        int c = wc * 32 + f * 16 + (l & 15);
        #pragma unroll
        for (int s = 0; s < 2; ++s) {
            int gk = (s << 2) + (l >> 4);
            aoff[f][s] = r * 64 + ((gk ^ (r & 7)) << 3);
            boff[f][s] = c * 64 + ((gk ^ (c & 7)) << 3);
        }
    }
    for (int k0 = 0; k0 < K; k0 += 64) {
        for (int g2 = tid; g2 < 512; g2 += 256) {
            int row = g2 >> 3, gc = g2 & 7;
            uint4 va = *reinterpret_cast<const uint4*>(Ab + (size_t)row * K + k0 + (gc << 3));
            *reinterpret_cast<uint4*>(As + row * 64 + ((gc ^ (row & 7)) << 3)) = va;
            uint4 vb = *reinterpret_cast<const uint4*>(Bb + (size_t)row * K + k0 + (gc << 3));
            *reinterpret_cast<uint4*>(Bs + row * 64 + ((gc ^ (row & 7)) << 3)) = vb;
        }
        __syncthreads();
        #pragma unroll
        for (int s = 0; s < 2; ++s) {
            bf16x8 av[2], bv[2];
            #pragma unroll
            for (int f = 0; f < 2; ++f) {
                av[f] = *reinterpret_cast<const bf16x8*>(As + aoff[f][s]);
                bv[f] = *reinterpret_cast<const bf16x8*>(Bs + boff[f][s]);
            }
            #pragma unroll
            for (int fa = 0; fa < 2; ++fa)
                #pragma unroll
                for (int fb = 0; fb < 2; ++fb)
                    acc[fa][fb] = __builtin_amdgcn_mfma_f32_16x16x32_bf16(
                        av[fa], bv[fb], acc[fa][fb], 0, 0, 0);
        }
        __syncthreads();
    }
}

union MidSMem {
    struct { unsigned short As[4096]; unsigned short Bs[4096]; } g;   // 16KB
    float stage[64][65];                                              // 16.6KB
};

// ---------------------------------------------------------------------------
// K2 mid: blocks 0..255 -> gemm1 (+fused src/dst); blocks 256+ -> edge atomicOr
// ---------------------------------------------------------------------------
__global__ __launch_bounds__(256) void mid(const unsigned short* __restrict__ xb,
                                           const unsigned short* __restrict__ Bt,
                                           const float* __restrict__ b1,
                                           const float* __restrict__ a1,
                                           const int* __restrict__ ei, int E,
                                           unsigned long long* __restrict__ adj,
                                           float* __restrict__ Wh1,
                                           float* __restrict__ src1,
                                           float* __restrict__ dst1) {
    __shared__ MidSMem sm;
    const int tid = threadIdx.x;
    const int l = tid & 63;
    const int wid = tid >> 6;

    if (blockIdx.x < 256) {
        const int u = blockIdx.x;
        const int rt = u & 63, h = u >> 6;
        f32x4 acc[2][2] = {};
        gemm_tile(xb + (size_t)(rt * 64) * NFEAT, Bt + (size_t)(h * 64) * NFEAT,
                  NFEAT, sm.g.As, sm.g.Bs, acc);
        const int wr = wid >> 1, wc = wid & 1;
        #pragma unroll
        for (int fa = 0; fa < 2; ++fa)
            #pragma unroll
            for (int fb = 0; fb < 2; ++fb) {
                int col = wc * 32 + fb * 16 + (l & 15);
                float bias = b1[h * NHID + col];
                #pragma unroll
                for (int j = 0; j < 4; ++j) {
                    int row = wr * 32 + fa * 16 + ((l >> 4) << 2) + j;
                    float v = acc[fa][fb][j] + bias;
                    Wh1[((size_t)h * N_NODES + rt * 64 + row) * NHID + col] = v;
                    sm.stage[row][col] = v;
                }
            }
        __syncthreads();
        for (int rr = 0; rr < 16; ++rr) {
            int row = wid * 16 + rr;
            float v = sm.stage[row][l];
            float s = v * a1[h * 2 * NHID + l];
            float d2 = v * a1[h * 2 * NHID + NHID + l];
            s = wredsum(s); d2 = wredsum(d2);
            if (l == 0) {
                src1[h * N_NODES + rt * 64 + row] = s;
                dst1[h * N_NODES + rt * 64 + row] = d2;
            }
        }
    } else {
        int t = (blockIdx.x - 256) * 256 + tid;
        if (t < E) {
            int r = ei[t];
            int c = ei[E + t];
            atomicOr(&adj[(size_t)r * 64 + (c >> 6)], 1ull << (c & 63));
        }
    }
}

// ---------------------------------------------------------------------------
// K3 attn layer 1: block = row (4 rows grid-strided), wave = head, lane = feat.
// Wave 0 compacts the row's bitmask into a sorted LDS list; writes bf16 h.
// ---------------------------------------------------------------------------
__global__ __launch_bounds__(256) void attn1(const unsigned long long* __restrict__ adj,
                                             const float* __restrict__ Wh1,
                                             const float* __restrict__ src1,
                                             const float* __restrict__ dst1,
                                             const float* __restrict__ ab1,
                                             unsigned short* __restrict__ hb) {
    __shared__ unsigned short nb[MAXD];
    __shared__ float ev[NHEADS][MAXD];
    __shared__ int sdeg;
    const int tid = threadIdx.x;
    const int l = tid & 63;
    const int h = tid >> 6;

    for (int i = blockIdx.x; i < N_NODES; i += 1024) {
        if (h == 0) {                     // wave 0: compact bitmask -> nb (sorted)
            unsigned long long w = adj[(size_t)i * 64 + l];
            int c = __popcll(w);
            int pre = c;
            #pragma unroll
            for (int o = 1; o < 64; o <<= 1) {
                int v = __shfl_up(pre, o);
                if (l >= o) pre += v;
            }
            int total = __shfl(pre, 63);
            int base = pre - c;
            if (l == 0) sdeg = total < MAXD ? total : MAXD;
            while (w) {
                int b = __builtin_ctzll(w); w &= w - 1;
                if (base < MAXD) nb[base] = (unsigned short)(l * 64 + b);
                ++base;
            }
        }
        __syncthreads();
        const int d = sdeg;
        const float s_i = src1[h * N_NODES + i];
        const float ab = ab1[h];
        const float* __restrict__ dsth = dst1 + h * N_NODES;
        const float* __restrict__ Whh = Wh1 + (size_t)h * N_NODES * NHID;
        int j0 = (l < d) ? nb[l] : -1;
        int j1 = (l + 64 < d) ? nb[l + 64] : -1;
        float s0 = (j0 >= 0) ? lrelu(s_i + dsth[j0] + ab) : -1e30f;
        float s1 = (j1 >= 0) ? lrelu(s_i + dsth[j1] + ab) : -1e30f;
        float m = wredmax(fmaxf(s0, s1));
        float e0 = (j0 >= 0) ? __expf(s0 - m) : 0.f;
        float e1 = (j1 >= 0) ? __expf(s1 - m) : 0.f;
        if (j0 >= 0) ev[h][l] = e0;
        if (j1 >= 0) ev[h][l + 64] = e1;
        float lsum = wredsum(e0 + e1);
        float acc = 0.f;
        if (d == 0) {                     // lazy colmean fallback (P ~ 5e-11)
            float s = 0.f;
            for (int j = 0; j < N_NODES; ++j) s += Whh[(size_t)j * NHID + l];
            acc = s * (1.f / N_NODES);
        } else {
            #pragma unroll 8
            for (int q = 0; q < d; ++q)
                acc += ev[h][q] * Whh[(size_t)nb[q] * NHID + l];
            acc *= (1.f / lsum);
        }
        float o = acc > 0.f ? acc : __expf(acc) - 1.f;   // elu
        hb[(size_t)i * (NHEADS * NHID) + h * NHID + l] = f2bf(o);
        __syncthreads();                  // nb/ev reuse next iteration
    }
}

// ---------------------------------------------------------------------------
// K4 gemm2 (+fused srco/dsto): grid 64, one 64-row tile each
// ---------------------------------------------------------------------------
__global__ __launch_bounds__(256) void gemm2(const unsigned short* __restrict__ hb,
                                             const unsigned short* __restrict__ Wot,
                                             const float* __restrict__ bo,
                                             const float* __restrict__ ao,
                                             float* __restrict__ Who,
                                             float* __restrict__ srco,
                                             float* __restrict__ dsto) {
    __shared__ MidSMem sm;
    const int tid = threadIdx.x;
    const int l = tid & 63;
    const int wid = tid >> 6;
    const int rt = blockIdx.x;
    f32x4 acc[2][2] = {};
    gemm_tile(hb + (size_t)(rt * 64) * (NHEADS * NHID), Wot,
              NHEADS * NHID, sm.g.As, sm.g.Bs, acc);
    const int wr = wid >> 1, wc = wid & 1;
    #pragma unroll
    for (int fa = 0; fa < 2; ++fa)
        #pragma unroll
        for (int fb = 0; fb < 2; ++fb) {
            int col = wc * 32 + fb * 16 + (l & 15);
            if (col < NCLASS) {
                float bias = bo[col];
                #pragma unroll
                for (int j = 0; j < 4; ++j) {
                    int row = wr * 32 + fa * 16 + ((l >> 4) << 2) + j;
                    float v = acc[fa][fb][j] + bias;
                    Who[(size_t)(rt * 64 + row) * NCLASS + col] = v;
                    sm.stage[row][col] = v;
                }
            }
        }
    __syncthreads();
    for (int rr = 0; rr < 16; ++rr) {
        int row = wid * 16 + rr;
        float v = (l < NCLASS) ? sm.stage[row][l] : 0.f;
        float s = (l < NCLASS) ? v * ao[l] : 0.f;
        float d2 = (l < NCLASS) ? v * ao[NCLASS + l] : 0.f;
        s = wredsum(s); d2 = wredsum(d2);
        if (l == 0) {
            srco[rt * 64 + row] = s;
            dsto[rt * 64 + row] = d2;
        }
    }
}

// ---------------------------------------------------------------------------
// K5 attn layer 2 + elu + log_softmax: 4 rows/block, wave = row.
// Each wave compacts its own row's bitmask.
// ---------------------------------------------------------------------------
__global__ __launch_bounds__(256) void attn2(const unsigned long long* __restrict__ adj,
                                             const float* __restrict__ Who,
                                             const float* __restrict__ srco,
                                             const float* __restrict__ dsto,
                                             const float* __restrict__ abo_p,
                                             float* __restrict__ out) {
    __shared__ unsigned short nb[4][MAXD];
    __shared__ float ev[4][MAXD];
    const int tid = threadIdx.x;
    const int wid = tid >> 6;
    const int l = tid & 63;
    const int i = blockIdx.x * 4 + wid;
    unsigned short* nbw = nb[wid];

    // per-wave compact of row i's bitmask (sorted)
    unsigned long long w = adj[(size_t)i * 64 + l];
    int c = __popcll(w);
    int pre = c;
    #pragma unroll
    for (int o = 1; o < 64; o <<= 1) {
        int v = __shfl_up(pre, o);
        if (l >= o) pre += v;
    }
    int total = __shfl(pre, 63);
    int base = pre - c;
    const int d = total < MAXD ? total : MAXD;
    while (w) {
        int b = __builtin_ctzll(w); w &= w - 1;
        if (base < MAXD) nbw[base] = (unsigned short)(l * 64 + b);
        ++base;
    }

    const float ab = abo_p[0];
    const float s_i = srco[i];
    int j0 = (l < d) ? nbw[l] : -1;
    int j1 = (l + 64 < d) ? nbw[l + 64] : -1;
    float s0 = (j0 >= 0) ? lrelu(s_i + dsto[j0] + ab) : -1e30f;
    float s1 = (j1 >= 0) ? lrelu(s_i + dsto[j1] + ab) : -1e30f;
    float m = wredmax(fmaxf(s0, s1));
    float e0 = (j0 >= 0) ? __expf(s0 - m) : 0.f;
    float e1 = (j1 >= 0) ? __expf(s1 - m) : 0.f;
    if (j0 >= 0) ev[wid][l] = e0;
    if (j1 >= 0) ev[wid][l + 64] = e1;
    float lsum = wredsum(e0 + e1);
    float acc = 0.f;
    if (d == 0) {
        if (l < NCLASS) {
            float s = 0.f;
            for (int j = 0; j < N_NODES; ++j) s += Who[(size_t)j * NCLASS + l];
            acc = s * (1.f / N_NODES);
        }
    } else if (l < NCLASS) {
        #pragma unroll 8
        for (int q = 0; q < d; ++q)
            acc += ev[wid][q] * Who[(size_t)nbw[q] * NCLASS + l];
        acc *= (1.f / lsum);
    }
    float v = acc > 0.f ? acc : __expf(acc) - 1.f;   // elu
    float xv = (l < NCLASS) ? v : -1e30f;
    float mx = wredmax(xv);
    float ex = (l < NCLASS) ? __expf(v - mx) : 0.f;
    ex = wredsum(ex);
    if (l < NCLASS) out[(size_t)i * NCLASS + l] = v - mx - logf(ex);
}

// ---------------------------------------------------------------------------
extern "C" void kernel_launch(void* const* d_in, const int* in_sizes, int n_in,
                              void* d_out, int out_size, void* d_ws, size_t ws_size,
                              hipStream_t stream) {
    const float* x   = (const float*)d_in[0];
    const int*   ei  = (const int*)d_in[1];
    const float* W1  = (const float*)d_in[2];
    const float* b1  = (const float*)d_in[3];
    const float* a1  = (const float*)d_in[4];
    const float* ab1 = (const float*)d_in[5];
    const float* Wo  = (const float*)d_in[6];
    const float* bo  = (const float*)d_in[7];
    const float* ao  = (const float*)d_in[8];
    const float* abo = (const float*)d_in[9];
    float* out = (float*)d_out;
    const int E = in_sizes[1] / 2;

    char* base = (char*)d_ws;
    const size_t MB = 1024 * 1024;
    unsigned long long* adj = (unsigned long long*)(base);                  // 2MB
    unsigned short* xb      = (unsigned short*)(base + 2 * MB);             // 4MB
    unsigned short* Bt      = (unsigned short*)(base + 6 * MB);             // 256KB
    unsigned short* Wot     = (unsigned short*)(base + 6 * MB + 262144);    // 32KB
    float*          Wh1     = (float*)(base + 7 * MB);                      // 4MB
    float*          src1    = (float*)(base + 11 * MB);                     // 64KB
    float*          dst1    = (float*)(base + 11 * MB + 65536);             // 64KB
    unsigned short* hb      = (unsigned short*)(base + 12 * MB);            // 2MB
    float*          Who     = (float*)(base + 14 * MB);                     // 640KB
    float*          srco    = (float*)(base + 15 * MB);                     // 16KB
    float*          dsto    = (float*)(base + 15 * MB + 16384);             // 16KB

    prep<<<960, 256, 0, stream>>>(x, W1, Wo, xb, Bt, Wot, (uint4*)adj);
    mid<<<256 + (E + 255) / 256, 256, 0, stream>>>(xb, Bt, b1, a1, ei, E, adj,
                                                   Wh1, src1, dst1);
    attn1<<<1024, 256, 0, stream>>>(adj, Wh1, src1, dst1, ab1, hb);
    gemm2<<<64, 256, 0, stream>>>(hb, Wot, bo, ao, Who, srco, dsto);
    attn2<<<N_NODES / 4, 256, 0, stream>>>(adj, Who, srco, dsto, abo, out);
}

// Round 8
// 61.071 us; speedup vs baseline: 14.3866x; 1.1359x over previous
//
#include <hip/hip_runtime.h>
#include <cstdint>
#include <cstddef>

#define N_NODES 4096
#define NFEAT   512
#define NHID    64
#define NCLASS  40
#define NHEADS  4
#define ALPHA_S 0.2f
#define MAXD    128

typedef __bf16 bf16x8 __attribute__((ext_vector_type(8)));
typedef float  f32x4  __attribute__((ext_vector_type(4)));

__device__ __forceinline__ float lrelu(float x) { return x > 0.f ? x : ALPHA_S * x; }

__device__ __forceinline__ unsigned short f2bf(float f) {
    unsigned u = __float_as_uint(f);
    u += 0x7fffu + ((u >> 16) & 1u);          // round-to-nearest-even
    return (unsigned short)(u >> 16);
}
__device__ __forceinline__ float bf2f(unsigned short v) {
    return __uint_as_float((unsigned)v << 16);
}

__device__ __forceinline__ float wredmax(float m) {
    #pragma unroll
    for (int o = 32; o; o >>= 1) m = fmaxf(m, __shfl_xor(m, o));
    return m;
}
__device__ __forceinline__ float wredsum(float s) {
    #pragma unroll
    for (int o = 32; o; o >>= 1) s += __shfl_xor(s, o);
    return s;
}

// ---------------------------------------------------------------------------
// K1 prep: x->bf16 cast, W1->Bt transpose-cast, Wo->Wot pad-cast, adj zero.
// grid: 512 (x) + 256 (Bt) + 64 (Wot) + 128 (adj zero) = 960
// ---------------------------------------------------------------------------
__global__ __launch_bounds__(256) void prep(const float* __restrict__ x,
                                            const float* __restrict__ W1,
                                            const float* __restrict__ Wo,
                                            unsigned short* __restrict__ xb,
                                            unsigned short* __restrict__ Bt,
                                            unsigned short* __restrict__ Wot,
                                            uint4* __restrict__ adj4) {
    const int u = blockIdx.x, tid = threadIdx.x;
    if (u < 512) {                        // x -> bf16, 4096 floats per block
        size_t idx = (size_t)u * 4096 + tid * 16;
        #pragma unroll
        for (int half = 0; half < 2; ++half) {
            float4 v0 = *reinterpret_cast<const float4*>(x + idx + half * 8);
            float4 v1 = *reinterpret_cast<const float4*>(x + idx + half * 8 + 4);
            uint4 o;
            o.x = (unsigned)f2bf(v0.x) | ((unsigned)f2bf(v0.y) << 16);
            o.y = (unsigned)f2bf(v0.z) | ((unsigned)f2bf(v0.w) << 16);
            o.z = (unsigned)f2bf(v1.x) | ((unsigned)f2bf(v1.y) << 16);
            o.w = (unsigned)f2bf(v1.z) | ((unsigned)f2bf(v1.w) << 16);
            *reinterpret_cast<uint4*>(xb + idx + half * 8) = o;
        }
    } else if (u < 768) {                 // W1 -> Bt[256][512] transposed
        int n = u - 512;
        int h = n >> 6, c = n & 63;
        for (int k = tid; k < NFEAT; k += 256)
            Bt[(size_t)n * NFEAT + k] = f2bf(W1[(size_t)h * NFEAT * NHID + (size_t)k * NHID + c]);
    } else if (u < 832) {                 // Wo -> Wot[64][256], cols>=40 zero
        int n = u - 768;
        unsigned short v = 0;
        if (n < NCLASS) v = f2bf(Wo[(size_t)tid * NCLASS + n]);
        Wot[(size_t)n * 256 + tid] = v;
    } else {                              // zero adj: 128 blocks x 1024 uint4
        uint4 z = {0, 0, 0, 0};
        uint4* p = adj4 + (size_t)(u - 832) * 1024 + tid;
        p[0] = z; p[256] = z; p[512] = z; p[768] = z;
    }
}

// ---------------------------------------------------------------------------
// 64x64 bf16 MFMA tile: C_acc += A[64xK] @ B[64xK]^T, XOR-swizzled LDS, 16x16x32
// ---------------------------------------------------------------------------
__device__ __forceinline__ void gemm_tile(const unsigned short* __restrict__ Ab,
                                          const unsigned short* __restrict__ Bb,
                                          int K, unsigned short* As, unsigned short* Bs,
                                          f32x4 acc[2][2]) {
    const int tid = threadIdx.x;
    const int l = tid & 63;
    const int wid = tid >> 6;
    const int wr = wid >> 1, wc = wid & 1;
    int aoff[2][2], boff[2][2];
    #pragma unroll
    for (int f = 0; f < 2; ++f) {
        int r = wr * 32 + f * 16 + (l & 15);
        int c = wc * 32 + f * 16 + (l & 15);
        #pragma unroll
        for (int s = 0; s < 2; ++s) {
            int gk = (s << 2) + (l >> 4);
            aoff[f][s] = r * 64 + ((gk ^ (r & 7)) << 3);
            boff[f][s] = c * 64 + ((gk ^ (c & 7)) << 3);
        }
    }
    for (int k0 = 0; k0 < K; k0 += 64) {
        for (int g2 = tid; g2 < 512; g2 += 256) {
            int row = g2 >> 3, gc = g2 & 7;
            uint4 va = *reinterpret_cast<const uint4*>(Ab + (size_t)row * K + k0 + (gc << 3));
            *reinterpret_cast<uint4*>(As + row * 64 + ((gc ^ (row & 7)) << 3)) = va;
            uint4 vb = *reinterpret_cast<const uint4*>(Bb + (size_t)row * K + k0 + (gc << 3));
            *reinterpret_cast<uint4*>(Bs + row * 64 + ((gc ^ (row & 7)) << 3)) = vb;
        }
        __syncthreads();
        #pragma unroll
        for (int s = 0; s < 2; ++s) {
            bf16x8 av[2], bv[2];
            #pragma unroll
            for (int f = 0; f < 2; ++f) {
                av[f] = *reinterpret_cast<const bf16x8*>(As + aoff[f][s]);
                bv[f] = *reinterpret_cast<const bf16x8*>(Bs + boff[f][s]);
            }
            #pragma unroll
            for (int fa = 0; fa < 2; ++fa)
                #pragma unroll
                for (int fb = 0; fb < 2; ++fb)
                    acc[fa][fb] = __builtin_amdgcn_mfma_f32_16x16x32_bf16(
                        av[fa], bv[fb], acc[fa][fb], 0, 0, 0);
        }
        __syncthreads();
    }
}

union MidSMem {
    struct { unsigned short As[4096]; unsigned short Bs[4096]; } g;   // 16KB
    float stage[64][65];                                              // 16.6KB
};

// ---------------------------------------------------------------------------
// K2 mid: blocks 0..255 -> gemm1 (+fused src/dst, bf16 Wh out);
//         blocks 256+  -> edge atomicOr scatter
// ---------------------------------------------------------------------------
__global__ __launch_bounds__(256) void mid(const unsigned short* __restrict__ xb,
                                           const unsigned short* __restrict__ Bt,
                                           const float* __restrict__ b1,
                                           const float* __restrict__ a1,
                                           const int* __restrict__ ei, int E,
                                           unsigned long long* __restrict__ adj,
                                           unsigned short* __restrict__ Wh1,
                                           float* __restrict__ src1,
                                           float* __restrict__ dst1) {
    __shared__ MidSMem sm;
    const int tid = threadIdx.x;
    const int l = tid & 63;
    const int wid = tid >> 6;

    if (blockIdx.x < 256) {
        const int u = blockIdx.x;
        const int rt = u & 63, h = u >> 6;
        f32x4 acc[2][2] = {};
        gemm_tile(xb + (size_t)(rt * 64) * NFEAT, Bt + (size_t)(h * 64) * NFEAT,
                  NFEAT, sm.g.As, sm.g.Bs, acc);
        const int wr = wid >> 1, wc = wid & 1;
        #pragma unroll
        for (int fa = 0; fa < 2; ++fa)
            #pragma unroll
            for (int fb = 0; fb < 2; ++fb) {
                int col = wc * 32 + fb * 16 + (l & 15);
                float bias = b1[h * NHID + col];
                #pragma unroll
                for (int j = 0; j < 4; ++j) {
                    int row = wr * 32 + fa * 16 + ((l >> 4) << 2) + j;
                    float v = acc[fa][fb][j] + bias;
                    Wh1[((size_t)h * N_NODES + rt * 64 + row) * NHID + col] = f2bf(v);
                    sm.stage[row][col] = v;
                }
            }
        __syncthreads();
        for (int rr = 0; rr < 16; ++rr) {
            int row = wid * 16 + rr;
            float v = sm.stage[row][l];
            float s = v * a1[h * 2 * NHID + l];
            float d2 = v * a1[h * 2 * NHID + NHID + l];
            s = wredsum(s); d2 = wredsum(d2);
            if (l == 0) {
                src1[h * N_NODES + rt * 64 + row] = s;
                dst1[h * N_NODES + rt * 64 + row] = d2;
            }
        }
    } else {
        int t = (blockIdx.x - 256) * 256 + tid;
        if (t < E) {
            int r = ei[t];
            int c = ei[E + t];
            atomicOr(&adj[(size_t)r * 64 + (c >> 6)], 1ull << (c & 63));
        }
    }
}

// ---------------------------------------------------------------------------
// K3 attn layer 1: block = row, wave = head, lane = feature.
// Wave 0 compacts the row's bitmask into a sorted LDS list; writes bf16 h.
// ---------------------------------------------------------------------------
__global__ __launch_bounds__(256) void attn1(const unsigned long long* __restrict__ adj,
                                             const unsigned short* __restrict__ Wh1,
                                             const float* __restrict__ src1,
                                             const float* __restrict__ dst1,
                                             const float* __restrict__ ab1,
                                             unsigned short* __restrict__ hb) {
    __shared__ unsigned short nb[MAXD];
    __shared__ float ev[NHEADS][MAXD];
    __shared__ int sdeg;
    const int tid = threadIdx.x;
    const int l = tid & 63;
    const int h = tid >> 6;
    const int i = blockIdx.x;

    if (h == 0) {                         // wave 0: compact bitmask -> nb (sorted)
        unsigned long long w = adj[(size_t)i * 64 + l];
        int c = __popcll(w);
        int pre = c;
        #pragma unroll
        for (int o = 1; o < 64; o <<= 1) {
            int v = __shfl_up(pre, o);
            if (l >= o) pre += v;
        }
        int total = __shfl(pre, 63);
        int base = pre - c;
        if (l == 0) sdeg = total < MAXD ? total : MAXD;
        while (w) {
            int b = __builtin_ctzll(w); w &= w - 1;
            if (base < MAXD) nb[base] = (unsigned short)(l * 64 + b);
            ++base;
        }
    }
    __syncthreads();
    const int d = sdeg;
    const float s_i = src1[h * N_NODES + i];
    const float ab = ab1[h];
    const float* __restrict__ dsth = dst1 + h * N_NODES;
    const unsigned short* __restrict__ Whh = Wh1 + (size_t)h * N_NODES * NHID;
    int j0 = (l < d) ? nb[l] : -1;
    int j1 = (l + 64 < d) ? nb[l + 64] : -1;
    float s0 = (j0 >= 0) ? lrelu(s_i + dsth[j0] + ab) : -1e30f;
    float s1 = (j1 >= 0) ? lrelu(s_i + dsth[j1] + ab) : -1e30f;
    float m = wredmax(fmaxf(s0, s1));
    float e0 = (j0 >= 0) ? __expf(s0 - m) : 0.f;
    float e1 = (j1 >= 0) ? __expf(s1 - m) : 0.f;
    if (j0 >= 0) ev[h][l] = e0;
    if (j1 >= 0) ev[h][l + 64] = e1;
    float lsum = wredsum(e0 + e1);
    float acc = 0.f;
    if (d == 0) {                         // lazy colmean fallback (P ~ 5e-11)
        float s = 0.f;
        for (int j = 0; j < N_NODES; ++j) s += bf2f(Whh[(size_t)j * NHID + l]);
        acc = s * (1.f / N_NODES);
    } else {
        #pragma unroll 8
        for (int q = 0; q < d; ++q)
            acc += ev[h][q] * bf2f(Whh[(size_t)nb[q] * NHID + l]);
        acc *= (1.f / lsum);
    }
    float o = acc > 0.f ? acc : __expf(acc) - 1.f;   // elu
    hb[(size_t)i * (NHEADS * NHID) + h * NHID + l] = f2bf(o);
}

// ---------------------------------------------------------------------------
// K4 gemm2 (+fused srco/dsto): grid 64, one 64-row tile each
// ---------------------------------------------------------------------------
__global__ __launch_bounds__(256) void gemm2(const unsigned short* __restrict__ hb,
                                             const unsigned short* __restrict__ Wot,
                                             const float* __restrict__ bo,
                                             const float* __restrict__ ao,
                                             float* __restrict__ Who,
                                             float* __restrict__ srco,
                                             float* __restrict__ dsto) {
    __shared__ MidSMem sm;
    const int tid = threadIdx.x;
    const int l = tid & 63;
    const int wid = tid >> 6;
    const int rt = blockIdx.x;
    f32x4 acc[2][2] = {};
    gemm_tile(hb + (size_t)(rt * 64) * (NHEADS * NHID), Wot,
              NHEADS * NHID, sm.g.As, sm.g.Bs, acc);
    const int wr = wid >> 1, wc = wid & 1;
    #pragma unroll
    for (int fa = 0; fa < 2; ++fa)
        #pragma unroll
        for (int fb = 0; fb < 2; ++fb) {
            int col = wc * 32 + fb * 16 + (l & 15);
            if (col < NCLASS) {
                float bias = bo[col];
                #pragma unroll
                for (int j = 0; j < 4; ++j) {
                    int row = wr * 32 + fa * 16 + ((l >> 4) << 2) + j;
                    float v = acc[fa][fb][j] + bias;
                    Who[(size_t)(rt * 64 + row) * NCLASS + col] = v;
                    sm.stage[row][col] = v;
                }
            }
        }
    __syncthreads();
    for (int rr = 0; rr < 16; ++rr) {
        int row = wid * 16 + rr;
        float v = (l < NCLASS) ? sm.stage[row][l] : 0.f;
        float s = (l < NCLASS) ? v * ao[l] : 0.f;
        float d2 = (l < NCLASS) ? v * ao[NCLASS + l] : 0.f;
        s = wredsum(s); d2 = wredsum(d2);
        if (l == 0) {
            srco[rt * 64 + row] = s;
            dsto[rt * 64 + row] = d2;
        }
    }
}

// ---------------------------------------------------------------------------
// K5 attn layer 2 + elu + log_softmax: 4 rows/block, wave = row.
// Each wave compacts its own row's bitmask.
// ---------------------------------------------------------------------------
__global__ __launch_bounds__(256) void attn2(const unsigned long long* __restrict__ adj,
                                             const float* __restrict__ Who,
                                             const float* __restrict__ srco,
                                             const float* __restrict__ dsto,
                                             const float* __restrict__ abo_p,
                                             float* __restrict__ out) {
    __shared__ unsigned short nb[4][MAXD];
    __shared__ float ev[4][MAXD];
    const int tid = threadIdx.x;
    const int wid = tid >> 6;
    const int l = tid & 63;
    const int i = blockIdx.x * 4 + wid;
    unsigned short* nbw = nb[wid];

    // per-wave compact of row i's bitmask (sorted)
    unsigned long long w = adj[(size_t)i * 64 + l];
    int c = __popcll(w);
    int pre = c;
    #pragma unroll
    for (int o = 1; o < 64; o <<= 1) {
        int v = __shfl_up(pre, o);
        if (l >= o) pre += v;
    }
    int total = __shfl(pre, 63);
    int base = pre - c;
    const int d = total < MAXD ? total : MAXD;
    while (w) {
        int b = __builtin_ctzll(w); w &= w - 1;
        if (base < MAXD) nbw[base] = (unsigned short)(l * 64 + b);
        ++base;
    }

    const float ab = abo_p[0];
    const float s_i = srco[i];
    int j0 = (l < d) ? nbw[l] : -1;
    int j1 = (l + 64 < d) ? nbw[l + 64] : -1;
    float s0 = (j0 >= 0) ? lrelu(s_i + dsto[j0] + ab) : -1e30f;
    float s1 = (j1 >= 0) ? lrelu(s_i + dsto[j1] + ab) : -1e30f;
    float m = wredmax(fmaxf(s0, s1));
    float e0 = (j0 >= 0) ? __expf(s0 - m) : 0.f;
    float e1 = (j1 >= 0) ? __expf(s1 - m) : 0.f;
    if (j0 >= 0) ev[wid][l] = e0;
    if (j1 >= 0) ev[wid][l + 64] = e1;
    float lsum = wredsum(e0 + e1);
    float acc = 0.f;
    if (d == 0) {
        if (l < NCLASS) {
            float s = 0.f;
            for (int j = 0; j < N_NODES; ++j) s += Who[(size_t)j * NCLASS + l];
            acc = s * (1.f / N_NODES);
        }
    } else if (l < NCLASS) {
        #pragma unroll 8
        for (int q = 0; q < d; ++q)
            acc += ev[wid][q] * Who[(size_t)nbw[q] * NCLASS + l];
        acc *= (1.f / lsum);
    }
    float v = acc > 0.f ? acc : __expf(acc) - 1.f;   // elu
    float xv = (l < NCLASS) ? v : -1e30f;
    float mx = wredmax(xv);
    float ex = (l < NCLASS) ? __expf(v - mx) : 0.f;
    ex = wredsum(ex);
    if (l < NCLASS) out[(size_t)i * NCLASS + l] = v - mx - logf(ex);
}

// ---------------------------------------------------------------------------
extern "C" void kernel_launch(void* const* d_in, const int* in_sizes, int n_in,
                              void* d_out, int out_size, void* d_ws, size_t ws_size,
                              hipStream_t stream) {
    const float* x   = (const float*)d_in[0];
    const int*   ei  = (const int*)d_in[1];
    const float* W1  = (const float*)d_in[2];
    const float* b1  = (const float*)d_in[3];
    const float* a1  = (const float*)d_in[4];
    const float* ab1 = (const float*)d_in[5];
    const float* Wo  = (const float*)d_in[6];
    const float* bo  = (const float*)d_in[7];
    const float* ao  = (const float*)d_in[8];
    const float* abo = (const float*)d_in[9];
    float* out = (float*)d_out;
    const int E = in_sizes[1] / 2;

    char* base = (char*)d_ws;
    const size_t MB = 1024 * 1024;
    unsigned long long* adj = (unsigned long long*)(base);                  // 2MB
    unsigned short* xb      = (unsigned short*)(base + 2 * MB);             // 4MB
    unsigned short* Bt      = (unsigned short*)(base + 6 * MB);             // 256KB
    unsigned short* Wot     = (unsigned short*)(base + 6 * MB + 262144);    // 32KB
    unsigned short* Wh1     = (unsigned short*)(base + 7 * MB);             // 2MB (bf16)
    float*          src1    = (float*)(base + 10 * MB);                     // 64KB
    float*          dst1    = (float*)(base + 10 * MB + 65536);             // 64KB
    unsigned short* hb      = (unsigned short*)(base + 12 * MB);            // 2MB
    float*          Who     = (float*)(base + 14 * MB);                     // 640KB
    float*          srco    = (float*)(base + 15 * MB);                     // 16KB
    float*          dsto    = (float*)(base + 15 * MB + 16384);             // 16KB

    prep<<<960, 256, 0, stream>>>(x, W1, Wo, xb, Bt, Wot, (uint4*)adj);
    mid<<<256 + (E + 255) / 256, 256, 0, stream>>>(xb, Bt, b1, a1, ei, E, adj,
                                                   Wh1, src1, dst1);
    attn1<<<N_NODES, 256, 0, stream>>>(adj, Wh1, src1, dst1, ab1, hb);
    gemm2<<<64, 256, 0, stream>>>(hb, Wot, bo, ao, Who, srco, dsto);
    attn2<<<N_NODES / 4, 256, 0, stream>>>(adj, Who, srco, dsto, abo, out);
}